// Round 1
// 137.855 us; speedup vs baseline: 1.0825x; 1.0825x over previous
//
#include <hip/hip_runtime.h>

// MorphologicalDilation: out[b,i,j,f] = max_{p in 0..8} (x[b, i+p/3, j+p%3, 0] + w[p, f])
// x: (16, 256, 256, 1) fp32, w: (1,1,1,9,32) fp32 -> out: (16, 254, 254, 32) fp32
//
// v2: 4 output rows per thread (i-blocking). Each thread loads 6 input rows
// (float4 + guarded float2) and the 9 w fragments ONCE for 4x4 pixels x 4 filters
// = 64 outputs (256 B). Halves-to-quarters the load-instruction count per output
// and 4x's the work behind each wave prologue -> attacks the issue/latency bound
// (kernel was ~71 us vs a ~21 us write floor; VALU demand only ~6 us).
//
// Layout unchanged: 8 lanes per pixel (lane owns a float4 of filters), 4 adjacent
// pixels along j per thread; 8 lanes x 16 B = one full 128 B line per pixel.

#define BB 16
#define HH 256
#define WW 256
#define FF 32
#define HO 254
#define WO 254
#define RPT 4   // output rows per thread

__device__ __forceinline__ float4 f4add(float a, float4 w) {
    return make_float4(a + w.x, a + w.y, a + w.z, a + w.w);
}
__device__ __forceinline__ float4 f4max(float4 a, float4 b) {
    return make_float4(fmaxf(a.x, b.x), fmaxf(a.y, b.y),
                       fmaxf(a.z, b.z), fmaxf(a.w, b.w));
}

__global__ __launch_bounds__(256) void
dilate_kernel(const float* __restrict__ x, const float* __restrict__ w,
              float* __restrict__ out) {
    const int fq = threadIdx.x & 7;        // filter quad: filters fq*4..fq*4+3
    const int pp = threadIdx.x >> 3;       // pixel group within block: 0..31
    const int j0 = (blockIdx.x << 7) + (pp << 2);  // 128 pixels per block along j
    const int i0 = blockIdx.y * RPT;       // first output row of this thread
    const int b  = blockIdx.z;

    // 9 w fragments into registers (reused for all RPT*4 pixels).
    const float4* __restrict__ w4 = (const float4*)w + fq;
    float4 wv[9];
#pragma unroll
    for (int p = 0; p < 9; ++p) wv[p] = w4[p * 8];

    // x window: rows i0..i0+5 (clamped; clamped rows feed only guarded-out
    // outputs), cols j0..j0+5 (float4 + guarded float2 per row).
    const bool tail_ok = (j0 + 5 < WW);    // false only for the last pixel group
    float xv[RPT + 2][6];
#pragma unroll
    for (int r = 0; r < RPT + 2; ++r) {
        int row = i0 + r;
        row = (row < HH) ? row : (HH - 1);
        const float* xb = x + ((b * HH + row) * WW + j0);
        const float4 lo = *(const float4*)xb;
        xv[r][0] = lo.x; xv[r][1] = lo.y; xv[r][2] = lo.z; xv[r][3] = lo.w;
        if (tail_ok) {
            const float2 hi = *(const float2*)(xb + 4);
            xv[r][4] = hi.x; xv[r][5] = hi.y;
        } else {
            xv[r][4] = 0.f; xv[r][5] = 0.f;  // feeds only out-of-range pixels
        }
    }

#pragma unroll
    for (int rr = 0; rr < RPT; ++rr) {
        const int i = i0 + rr;
        if (i < HO) {                      // only last y-block has a 2-row tail
            float4* o4 = (float4*)out + (((b * HO + i) * WO + j0) * 8 + fq);
#pragma unroll
            for (int k = 0; k < 4; ++k) {
                // 9 sums, max3-shaped tree: max3(s012), max3(s345), max3(s678),
                // then max3(t0,t1,t2).
                float4 t0, t1, t2;
#pragma unroll
                for (int r = 0; r < 3; ++r) {
                    float4 s0 = f4add(xv[rr + r][k + 0], wv[r * 3 + 0]);
                    float4 s1 = f4add(xv[rr + r][k + 1], wv[r * 3 + 1]);
                    float4 s2 = f4add(xv[rr + r][k + 2], wv[r * 3 + 2]);
                    float4 t  = f4max(f4max(s0, s1), s2);   // -> v_max3_f32
                    if (r == 0) t0 = t; else if (r == 1) t1 = t; else t2 = t;
                }
                const float4 m = f4max(f4max(t0, t1), t2);  // -> v_max3_f32

                if (j0 + k < WO) o4[k * 8] = m;
            }
        }
    }
}

extern "C" void kernel_launch(void* const* d_in, const int* in_sizes, int n_in,
                              void* d_out, int out_size, void* d_ws, size_t ws_size,
                              hipStream_t stream) {
    const float* x = (const float*)d_in[0];
    const float* w = (const float*)d_in[1];
    float* out = (float*)d_out;

    dim3 grid((WO + 127) / 128, (HO + RPT - 1) / RPT, BB);   // (2, 64, 16)
    dilate_kernel<<<grid, 256, 0, stream>>>(x, w, out);
}